// Round 4
// baseline (1463.752 us; speedup 1.0000x reference)
//
#include <hip/hip_runtime.h>
#include <stdint.h>
#include <float.h>

#define K_DIM 2048
#define M_TOK 16384
#define N_EMB 16384
#define NKT 32  // K-tiles of 64

typedef __bf16 bf16x8 __attribute__((ext_vector_type(8)));
typedef float f32x4 __attribute__((ext_vector_type(4)));
typedef unsigned long long u64;

__device__ __forceinline__ ushort f2bf_rne(float f) {
  uint32_t u = __float_as_uint(f);
  u += 0x7FFFu + ((u >> 16) & 1u);
  return (ushort)(u >> 16);
}
__device__ __forceinline__ uint32_t f2key(float f) {
  uint32_t u = __float_as_uint(f);
  return (u & 0x80000000u) ? ~u : (u | 0x80000000u);
}
__device__ __forceinline__ float key2f(uint32_t k) {
  uint32_t b = (k & 0x80000000u) ? (k & 0x7FFFFFFFu) : ~k;
  return __uint_as_float(b);
}
__device__ __forceinline__ float ulpf(float v) {
  uint32_t e = __float_as_uint(v) & 0x7f800000u;
  return __uint_as_float(e) * 1.1920929e-7f;  // 2^-23
}

// ---------------- fp32 -> bf16 (RNE) ----------------

__global__ void tobf16_kernel(const float* __restrict__ in, ushort* __restrict__ out) {
  long i = ((long)blockIdx.x * 256 + threadIdx.x) * 8;
  float4 a = *reinterpret_cast<const float4*>(in + i);
  float4 b = *reinterpret_cast<const float4*>(in + i + 4);
  ushort4 ha, hb;
  ha.x = f2bf_rne(a.x); ha.y = f2bf_rne(a.y); ha.z = f2bf_rne(a.z); ha.w = f2bf_rne(a.w);
  hb.x = f2bf_rne(b.x); hb.y = f2bf_rne(b.y); hb.z = f2bf_rne(b.z); hb.w = f2bf_rne(b.w);
  *reinterpret_cast<ushort4*>(out + i) = ha;
  *reinterpret_cast<ushort4*>(out + i + 4) = hb;
}

// ------- xx = np.sum(x*x, axis=1) replicating numpy AVX512 pairwise_sum -------

__global__ void xx_kernel(const float* __restrict__ x, float* __restrict__ xxArr) {
#pragma clang fp contract(off)
  int row = blockIdx.x * 16 + (threadIdx.x >> 4);
  int blk = threadIdx.x & 15;
  const float* p = x + (long)row * K_DIM + blk * 128;
  float S[16];
#pragma unroll
  for (int L = 0; L < 16; ++L) {
    float p0 = p[L] * p[L];
    float p1 = p[L + 16] * p[L + 16];
    float p2 = p[L + 32] * p[L + 32];
    float p3 = p[L + 48] * p[L + 48];
    float p4 = p[L + 64] * p[L + 64];
    float p5 = p[L + 80] * p[L + 80];
    float p6 = p[L + 96] * p[L + 96];
    float p7 = p[L + 112] * p[L + 112];
    S[L] = ((p0 + p1) + (p2 + p3)) + ((p4 + p5) + (p6 + p7));
  }
  float T1[8], T3[4];
#pragma unroll
  for (int L = 0; L < 8; ++L) T1[L] = S[L] + S[L + 8];
#pragma unroll
  for (int L = 0; L < 4; ++L) T3[L] = T1[L] + T1[L + 4];
  float blksum = (T3[0] + T3[2]) + (T3[1] + T3[3]);
  __shared__ float lds[16][16];
  lds[threadIdx.x >> 4][blk] = blksum;
  __syncthreads();
  if (blk == 0) {
    const float* b = lds[threadIdx.x >> 4];
    float r1[8], r2[4];
#pragma unroll
    for (int i = 0; i < 8; ++i) r1[i] = b[2 * i] + b[2 * i + 1];
#pragma unroll
    for (int i = 0; i < 4; ++i) r2[i] = r1[2 * i] + r1[2 * i + 1];
    xxArr[row] = (r2[0] + r2[1]) + (r2[2] + r2[3]);
  }
}

// ---------------- bf16 GEMM + per-stripe top-2 coarse argmin ----------------
// 256x128 tile, BK=64, 8 waves (4m x 2n), per-wave 64x64 out (4x4 frags).
// LDS: 3 rotating 48KB buffers {A 256x64, B 128x64} bf16 = 144 KiB.
// XOR-swizzle col^((row&7)<<3) via pre-swizzled global source (rule #21).
// 2 phases/tile, stage interleaved (T3), counted vmcnt(6) (T4), setprio (T5).

#define GLOAD_LDS16(g, s)                                              \
  __builtin_amdgcn_global_load_lds(                                    \
      (const __attribute__((address_space(1))) void*)(g),              \
      (__attribute__((address_space(3))) void*)(s), 16, 0, 0)

__global__ __launch_bounds__(512, 2) void gemm_argmin_kernel(
    const ushort* __restrict__ xh, const ushort* __restrict__ eh,
    u64* __restrict__ stripes) {
  __shared__ __attribute__((aligned(16))) ushort lds[73728];  // 144 KiB

  int b = blockIdx.x;
  int wg = (b & 7) * 1024 + (b >> 3);  // XCD-aware swizzle (8192 % 8 == 0)
  int bx = wg & 127, by = wg >> 7;
  int m0 = by * 256, n0 = bx * 128;

  int t = threadIdx.x;
  int lane = t & 63, wid = t >> 6;
  int wm = wid >> 1, wn = wid & 1;
  int arow = lane & 15;
  int kg8 = (lane >> 4) * 8;

  // staging: thread t covers LDS row (t>>3), 16B chunk (t&7); global col
  // pre-swizzled so linear global_load_lds dest + swizzled ds_read match.
  int srow = t >> 3;
  int swz8 = (((t & 7) ^ (srow & 7)) << 3);
  const ushort* gA = xh + (unsigned)(m0 + srow) * 2048u + swz8;
  const ushort* gB = eh + (unsigned)(n0 + srow) * 2048u + swz8;

  // A rows g*64+srow at buf + g*4096 + t*8 ; B (128 rows) at buf + 16384.
#define STAGE_P0(KT, BS)                                               \
  {                                                                    \
    const ushort* _ga = gA + (KT) * 64;                                \
    ushort* _l = (ushort*)lds + (BS) * 24576 + t * 8;                  \
    GLOAD_LDS16(_ga, _l);                                              \
    GLOAD_LDS16(_ga + 131072, _l + 4096);                              \
    GLOAD_LDS16(gB + (KT) * 64, _l + 16384);                           \
  }
#define STAGE_P1(KT, BS)                                               \
  {                                                                    \
    const ushort* _ga = gA + (KT) * 64 + 262144;                       \
    ushort* _l = (ushort*)lds + (BS) * 24576 + t * 8;                  \
    GLOAD_LDS16(_ga, _l + 8192);                                       \
    GLOAD_LDS16(_ga + 131072, _l + 12288);                             \
    GLOAD_LDS16(gB + (KT) * 64 + 131072, _l + 20480);                  \
  }

  f32x4 acc[4][4] = {};
  int xr = (arow & 7) << 3;
  int ck0 = kg8 ^ xr;          // swizzled col offset, k-step 0
  int ck1 = (32 + kg8) ^ xr;   // k-step 1

  STAGE_P0(0, 0); STAGE_P1(0, 0);
  STAGE_P0(1, 1); STAGE_P1(1, 1);
  asm volatile("s_waitcnt vmcnt(6)" ::: "memory");  // tile 0 landed
  __builtin_amdgcn_s_barrier();

  int cb = 0, sb = 2;
  for (int kt = 0; kt < NKT; ++kt) {
    const ushort* Ab = (const ushort*)lds + cb * 24576;
    const ushort* Bb = Ab + 16384;

    // ---------- phase 0: k-step 0 ----------
    bf16x8 a0[4], b0[4];
#pragma unroll
    for (int i = 0; i < 4; ++i)
      a0[i] = *reinterpret_cast<const bf16x8*>(Ab + (wm * 64 + i * 16 + arow) * 64 + ck0);
#pragma unroll
    for (int j = 0; j < 4; ++j)
      b0[j] = *reinterpret_cast<const bf16x8*>(Bb + (wn * 64 + j * 16 + arow) * 64 + ck0);
    if (kt < NKT - 2) STAGE_P0(kt + 2, sb);
    __builtin_amdgcn_s_barrier();
    asm volatile("s_waitcnt lgkmcnt(0)" ::: "memory");
    __builtin_amdgcn_sched_barrier(0);
    __builtin_amdgcn_s_setprio(1);
#pragma unroll
    for (int i = 0; i < 4; ++i)
#pragma unroll
      for (int j = 0; j < 4; ++j)
        acc[i][j] = __builtin_amdgcn_mfma_f32_16x16x32_bf16(a0[i], b0[j], acc[i][j], 0, 0, 0);
    __builtin_amdgcn_s_setprio(0);
    __builtin_amdgcn_s_barrier();

    // ---------- phase 1: k-step 1 ----------
    bf16x8 a1[4], b1[4];
#pragma unroll
    for (int i = 0; i < 4; ++i)
      a1[i] = *reinterpret_cast<const bf16x8*>(Ab + (wm * 64 + i * 16 + arow) * 64 + ck1);
#pragma unroll
    for (int j = 0; j < 4; ++j)
      b1[j] = *reinterpret_cast<const bf16x8*>(Bb + (wn * 64 + j * 16 + arow) * 64 + ck1);
    if (kt < NKT - 2) {
      STAGE_P1(kt + 2, sb);
      asm volatile("s_waitcnt vmcnt(6)" ::: "memory");  // kt+1 landed; kt+2 flies
    } else {
      asm volatile("s_waitcnt vmcnt(0)" ::: "memory");  // tail drain
    }
    __builtin_amdgcn_s_barrier();
    asm volatile("s_waitcnt lgkmcnt(0)" ::: "memory");
    __builtin_amdgcn_sched_barrier(0);
    __builtin_amdgcn_s_setprio(1);
#pragma unroll
    for (int i = 0; i < 4; ++i)
#pragma unroll
      for (int j = 0; j < 4; ++j)
        acc[i][j] = __builtin_amdgcn_mfma_f32_16x16x32_bf16(a1[i], b1[j], acc[i][j], 0, 0, 0);
    __builtin_amdgcn_s_setprio(0);
    __builtin_amdgcn_s_barrier();

    cb = (cb == 2) ? 0 : cb + 1;
    sb = (sb == 2) ? 0 : sb + 1;
  }

  // epilogue: per-row top-2 over this wave's 64 columns; score = -2*dot
  int stripe = (bx << 1) + wn;  // 0..255
#pragma unroll
  for (int i = 0; i < 4; ++i) {
#pragma unroll
    for (int r = 0; r < 4; ++r) {
      uint32_t p1 = 0xFFFFFFFFu, p2 = 0xFFFFFFFFu;
#pragma unroll
      for (int j = 0; j < 4; ++j) {
        float sv = -2.0f * acc[i][j][r];
        uint32_t n = (uint32_t)(n0 + wn * 64 + j * 16 + arow);
        uint32_t pk = ((f2key(sv) >> 14) << 14) | n;
        if (pk < p1) { p2 = p1; p1 = pk; }
        else if (pk < p2) { p2 = pk; }
      }
#pragma unroll
      for (int ms = 1; ms < 16; ms <<= 1) {
        uint32_t q1 = __shfl_xor(p1, ms, 64);
        uint32_t q2 = __shfl_xor(p2, ms, 64);
        uint32_t m1 = min(p1, q1);
        uint32_t m2 = min(max(p1, q1), min(p2, q2));
        p1 = m1; p2 = m2;
      }
      if ((lane & 15) == 0) {
        long gm = m0 + wm * 64 + i * 16 + (lane >> 4) * 4 + r;
        stripes[gm * 256 + stripe] = ((u64)p1 << 32) | p2;
      }
    }
  }
#undef STAGE_P0
#undef STAGE_P1
}

// ---- resolve: emulate np fp32 d = fl(xx - 2*fl(dot)), argmin, tie->lowest n ----

__global__ void resolve_kernel(const u64* __restrict__ stripes,
                               const float* __restrict__ x,
                               const float* __restrict__ emb,
                               const float* __restrict__ xxArr,
                               float* __restrict__ outIdxF,
                               int* __restrict__ idxOut) {
#pragma clang fp contract(off)
  int w = threadIdx.x >> 6;
  int row = blockIdx.x * 4 + w;
  int lane = threadIdx.x & 63;
  const u64* sp = stripes + (long)row * 256;

  uint32_t mine[8];
  uint32_t pmin = 0xFFFFFFFFu;
#pragma unroll
  for (int q = 0; q < 4; ++q) {
    u64 v = sp[lane + q * 64];
    mine[2 * q] = (uint32_t)(v >> 32);
    mine[2 * q + 1] = (uint32_t)v;
    pmin = min(pmin, mine[2 * q]);
  }
#pragma unroll
  for (int ms = 1; ms < 64; ms <<= 1) pmin = min(pmin, __shfl_xor(pmin, ms, 64));

  float xxf = xxArr[row];
  float smin_lb = key2f((pmin >> 14) << 14);
  float thr = smin_lb + ulpf(fabsf(xxf) + 0.03f) + 1e-4f;
  uint32_t kthr = f2key(thr) >> 14;

  int cnt = 0;
#pragma unroll
  for (int q = 0; q < 8; ++q) cnt += ((mine[q] >> 14) <= kthr) ? 1 : 0;
#pragma unroll
  for (int ms = 1; ms < 64; ms <<= 1) cnt += __shfl_xor(cnt, ms, 64);

  __shared__ int cand[4][32];
  __shared__ int ccount[4];
  bool need = (cnt > 1);
  if (lane == 0) ccount[w] = 0;
  __syncthreads();
  if (need) {
#pragma unroll
    for (int q = 0; q < 8; ++q) {
      if ((mine[q] >> 14) <= kthr) {
        int slot = atomicAdd(&ccount[w], 1);
        if (slot < 32) cand[w][slot] = (int)(mine[q] & 0x3FFFu);
      }
    }
  }
  __syncthreads();

  int winner;
  if (!need) {
    winner = (int)(pmin & 0x3FFFu);
  } else {
    int nc = min(ccount[w], 32);
    float bestd = FLT_MAX;
    int bestn = 0x7fffffff;
    const float* xr = x + (long)row * K_DIM;
    for (int c = 0; c < nc; ++c) {
      int n = cand[w][c];
      const float* er = emb + (long)n * K_DIM;
      double ds = 0.0;
      for (int k = lane; k < K_DIM; k += 64)
        ds += (double)xr[k] * (double)er[k];
#pragma unroll
      for (int ms = 1; ms < 64; ms <<= 1) ds += __shfl_xor(ds, ms, 64);
      float dotf = (float)ds;
      float t2 = 2.0f * dotf;
      float dq = xxf - t2;
      if (dq < bestd || (dq == bestd && n < bestn)) { bestd = dq; bestn = n; }
    }
    winner = bestn;
  }
  if (lane == 0) { outIdxF[row] = (float)winner; idxOut[row] = winner; }
}

// ---------------- gather z_q = embedding[idx] ----------------

__global__ void gather_kernel(const float* __restrict__ emb,
                              const int* __restrict__ idx,
                              float* __restrict__ zq) {
  int row = blockIdx.x, t = threadIdx.x;
  long n = idx[row];
  const float4* s = reinterpret_cast<const float4*>(emb + n * K_DIM);
  float4* d = reinterpret_cast<float4*>(zq + (long)row * K_DIM);
  d[t] = s[t];
  d[t + 256] = s[t + 256];
}

// ---------------- launch ----------------

extern "C" void kernel_launch(void* const* d_in, const int* in_sizes, int n_in,
                              void* d_out, int out_size, void* d_ws, size_t ws_size,
                              hipStream_t stream) {
  const float* x = (const float*)d_in[0];
  const float* emb = (const float*)d_in[1];
  float* out = (float*)d_out;

  char* ws = (char*)d_ws;
  ushort* xh = (ushort*)ws;                               // 64 MiB
  u64* stripes = (u64*)(ws + 67108864);                   // 32 MiB
  float* xxArr = (float*)(ws + 100663296);                // 64 KiB
  int* idxbuf = (int*)(ws + 100728832);                   // 64 KiB

  ushort* ehh = (ushort*)d_out;                           // 64 MiB (overlay, gather overwrites)

  tobf16_kernel<<<16384, 256, 0, stream>>>(x, xh);
  tobf16_kernel<<<16384, 256, 0, stream>>>(emb, ehh);
  xx_kernel<<<1024, 256, 0, stream>>>(x, xxArr);
  gemm_argmin_kernel<<<8192, 512, 0, stream>>>(xh, ehh, stripes);
  resolve_kernel<<<4096, 256, 0, stream>>>(stripes, x, emb, xxArr, out + 33554432, idxbuf);
  gather_kernel<<<16384, 256, 0, stream>>>(emb, idxbuf, out);
}

// Round 5
// 1342.688 us; speedup vs baseline: 1.0902x; 1.0902x over previous
//
#include <hip/hip_runtime.h>
#include <stdint.h>
#include <float.h>

#define K_DIM 2048
#define M_TOK 16384
#define N_EMB 16384
#define NKT 64  // K-tiles of 32

typedef __bf16 bf16x8 __attribute__((ext_vector_type(8)));
typedef float f32x4 __attribute__((ext_vector_type(4)));
typedef unsigned long long u64;

__device__ __forceinline__ ushort f2bf_rne(float f) {
  uint32_t u = __float_as_uint(f);
  u += 0x7FFFu + ((u >> 16) & 1u);
  return (ushort)(u >> 16);
}
__device__ __forceinline__ uint32_t f2key(float f) {
  uint32_t u = __float_as_uint(f);
  return (u & 0x80000000u) ? ~u : (u | 0x80000000u);
}
__device__ __forceinline__ float key2f(uint32_t k) {
  uint32_t b = (k & 0x80000000u) ? (k & 0x7FFFFFFFu) : ~k;
  return __uint_as_float(b);
}
__device__ __forceinline__ float ulpf(float v) {
  uint32_t e = __float_as_uint(v) & 0x7f800000u;
  return __uint_as_float(e) * 1.1920929e-7f;  // 2^-23
}

// ---------------- fp32 -> bf16 (RNE) ----------------

__global__ void tobf16_kernel(const float* __restrict__ in, ushort* __restrict__ out) {
  long i = ((long)blockIdx.x * 256 + threadIdx.x) * 8;
  float4 a = *reinterpret_cast<const float4*>(in + i);
  float4 b = *reinterpret_cast<const float4*>(in + i + 4);
  ushort4 ha, hb;
  ha.x = f2bf_rne(a.x); ha.y = f2bf_rne(a.y); ha.z = f2bf_rne(a.z); ha.w = f2bf_rne(a.w);
  hb.x = f2bf_rne(b.x); hb.y = f2bf_rne(b.y); hb.z = f2bf_rne(b.z); hb.w = f2bf_rne(b.w);
  *reinterpret_cast<ushort4*>(out + i) = ha;
  *reinterpret_cast<ushort4*>(out + i + 4) = hb;
}

// ------- xx = np.sum(x*x, axis=1) replicating numpy AVX512 pairwise_sum -------

__global__ void xx_kernel(const float* __restrict__ x, float* __restrict__ xxArr) {
#pragma clang fp contract(off)
  int row = blockIdx.x * 16 + (threadIdx.x >> 4);
  int blk = threadIdx.x & 15;
  const float* p = x + (long)row * K_DIM + blk * 128;
  float S[16];
#pragma unroll
  for (int L = 0; L < 16; ++L) {
    float p0 = p[L] * p[L];
    float p1 = p[L + 16] * p[L + 16];
    float p2 = p[L + 32] * p[L + 32];
    float p3 = p[L + 48] * p[L + 48];
    float p4 = p[L + 64] * p[L + 64];
    float p5 = p[L + 80] * p[L + 80];
    float p6 = p[L + 96] * p[L + 96];
    float p7 = p[L + 112] * p[L + 112];
    S[L] = ((p0 + p1) + (p2 + p3)) + ((p4 + p5) + (p6 + p7));
  }
  float T1[8], T3[4];
#pragma unroll
  for (int L = 0; L < 8; ++L) T1[L] = S[L] + S[L + 8];
#pragma unroll
  for (int L = 0; L < 4; ++L) T3[L] = T1[L] + T1[L + 4];
  float blksum = (T3[0] + T3[2]) + (T3[1] + T3[3]);
  __shared__ float lds[16][16];
  lds[threadIdx.x >> 4][blk] = blksum;
  __syncthreads();
  if (blk == 0) {
    const float* b = lds[threadIdx.x >> 4];
    float r1[8], r2[4];
#pragma unroll
    for (int i = 0; i < 8; ++i) r1[i] = b[2 * i] + b[2 * i + 1];
#pragma unroll
    for (int i = 0; i < 4; ++i) r2[i] = r1[2 * i] + r1[2 * i + 1];
    xxArr[row] = (r2[0] + r2[1]) + (r2[2] + r2[3]);
  }
}

// ---------------- bf16 GEMM + per-stripe top-2 coarse argmin ----------------
// 256x256 tile, BK=32, 8 waves (2m x 4n), per-wave 128x64 out (8x4 frags).
// LDS: 4 rotating 32KB buffers {A 256x32, B 256x32} = 128 KiB; 3-deep
// prefetch; ONE barrier per K-tile; counted vmcnt(8) (T4); setprio (T5).
// Swizzle for 64B rows: chunk ^= (row>>1)&3, applied on global source (write
// side) and ds_read offset (read side) — both-sides-or-neither (rule #21).

#define GLOAD_LDS16(g, s)                                              \
  __builtin_amdgcn_global_load_lds(                                    \
      (const __attribute__((address_space(1))) void*)(g),              \
      (__attribute__((address_space(3))) void*)(s), 16, 0, 0)

__global__ __launch_bounds__(512, 2) void gemm_argmin_kernel(
    const ushort* __restrict__ xh, const ushort* __restrict__ eh,
    u64* __restrict__ stripes) {
  __shared__ __attribute__((aligned(16))) ushort lds[65536];  // 128 KiB

  int b = blockIdx.x;
  int wg = (b & 7) * 512 + (b >> 3);  // XCD-aware swizzle (4096 % 8 == 0)
  int bx = wg & 63, by = wg >> 6;
  int m0 = by * 256, n0 = bx * 256;

  int t = threadIdx.x;
  int lane = t & 63, wid = t >> 6;
  int wm = wid >> 2, wn = wid & 3;
  int arow = lane & 15;
  int kg8 = (lane >> 4) * 8;

  // staging: thread t covers LDS row (t>>2) (+128 for 2nd gload), chunk (t&3);
  // global chunk pre-swizzled: g = (t&3) ^ ((t>>3)&3)  [= chunk ^ ((row>>1)&3)]
  int swzel = ((t & 3) ^ ((t >> 3) & 3)) * 8;
  const ushort* gA = xh + (unsigned)(m0 + (t >> 2)) * 2048u + swzel;
  const ushort* gB = eh + (unsigned)(n0 + (t >> 2)) * 2048u + swzel;

#define STAGE(KT, BS)                                                  \
  {                                                                    \
    const ushort* _ga = gA + (KT) * 32;                                \
    const ushort* _gb = gB + (KT) * 32;                                \
    ushort* _l = (ushort*)lds + (BS) * 16384 + t * 8;                  \
    GLOAD_LDS16(_ga, _l);                                              \
    GLOAD_LDS16(_ga + 262144, _l + 4096);                              \
    GLOAD_LDS16(_gb, _l + 8192);                                       \
    GLOAD_LDS16(_gb + 262144, _l + 12288);                             \
  }

  f32x4 acc[8][4] = {};
  // read-side swizzled column offset (elements): chunk = kg8>>3, row-XOR (arow>>1)&3
  int ckq = kg8 ^ (((arow >> 1) & 3) << 3);

#define FRAG_READS(KT)                                                 \
  const ushort* Ab = (const ushort*)lds + ((KT) & 3) * 16384;          \
  const ushort* Bb = Ab + 8192;                                        \
  bf16x8 af[8], bf4[4];                                                \
  _Pragma("unroll") for (int i = 0; i < 8; ++i)                        \
      af[i] = *reinterpret_cast<const bf16x8*>(                        \
          Ab + (wm * 128 + i * 16 + arow) * 32 + ckq);                 \
  _Pragma("unroll") for (int j = 0; j < 4; ++j)                        \
      bf4[j] = *reinterpret_cast<const bf16x8*>(                       \
          Bb + (wn * 64 + j * 16 + arow) * 32 + ckq);

#define MFMA32()                                                       \
  __builtin_amdgcn_s_setprio(1);                                       \
  _Pragma("unroll") for (int i = 0; i < 8; ++i)                        \
      _Pragma("unroll") for (int j = 0; j < 4; ++j)                    \
          acc[i][j] = __builtin_amdgcn_mfma_f32_16x16x32_bf16(         \
              af[i], bf4[j], acc[i][j], 0, 0, 0);                      \
  __builtin_amdgcn_s_setprio(0);

  // prologue: 3 tiles in flight
  STAGE(0, 0);
  STAGE(1, 1);
  STAGE(2, 2);
  asm volatile("s_waitcnt vmcnt(8)" ::: "memory");  // tile 0 landed
  __builtin_amdgcn_s_barrier();

  for (int kt = 0; kt < NKT - 3; ++kt) {
    FRAG_READS(kt);
    STAGE(kt + 3, (kt + 3) & 3);
    MFMA32();
    asm volatile("s_waitcnt vmcnt(8)" ::: "memory");  // kt+1 landed; kt+2,kt+3 fly
    __builtin_amdgcn_s_barrier();
  }
  {  // kt = 61
    FRAG_READS(NKT - 3);
    MFMA32();
    asm volatile("s_waitcnt vmcnt(4)" ::: "memory");  // tile 62 landed
    __builtin_amdgcn_s_barrier();
  }
  {  // kt = 62
    FRAG_READS(NKT - 2);
    MFMA32();
    asm volatile("s_waitcnt vmcnt(0)" ::: "memory");  // tile 63 landed
    __builtin_amdgcn_s_barrier();
  }
  {  // kt = 63
    FRAG_READS(NKT - 1);
    MFMA32();
  }

  // epilogue: per-row top-2 over this wave's 64 columns; score = -2*dot
  int stripe = (bx << 2) + wn;  // 0..255
#pragma unroll
  for (int i = 0; i < 8; ++i) {
#pragma unroll
    for (int r = 0; r < 4; ++r) {
      uint32_t p1 = 0xFFFFFFFFu, p2 = 0xFFFFFFFFu;
#pragma unroll
      for (int j = 0; j < 4; ++j) {
        float sv = -2.0f * acc[i][j][r];
        uint32_t n = (uint32_t)(n0 + wn * 64 + j * 16 + arow);
        uint32_t pk = ((f2key(sv) >> 14) << 14) | n;
        if (pk < p1) { p2 = p1; p1 = pk; }
        else if (pk < p2) { p2 = pk; }
      }
#pragma unroll
      for (int ms = 1; ms < 16; ms <<= 1) {
        uint32_t q1 = __shfl_xor(p1, ms, 64);
        uint32_t q2 = __shfl_xor(p2, ms, 64);
        uint32_t m1 = min(p1, q1);
        uint32_t m2 = min(max(p1, q1), min(p2, q2));
        p1 = m1; p2 = m2;
      }
      if ((lane & 15) == 0) {
        long gm = m0 + wm * 128 + i * 16 + (lane >> 4) * 4 + r;
        stripes[gm * 256 + stripe] = ((u64)p1 << 32) | p2;
      }
    }
  }
#undef STAGE
#undef FRAG_READS
#undef MFMA32
}

// ---- resolve: emulate np fp32 d = fl(xx - 2*fl(dot)), argmin, tie->lowest n ----

__global__ void resolve_kernel(const u64* __restrict__ stripes,
                               const float* __restrict__ x,
                               const float* __restrict__ emb,
                               const float* __restrict__ xxArr,
                               float* __restrict__ outIdxF,
                               int* __restrict__ idxOut) {
#pragma clang fp contract(off)
  int w = threadIdx.x >> 6;
  int row = blockIdx.x * 4 + w;
  int lane = threadIdx.x & 63;
  const u64* sp = stripes + (long)row * 256;

  uint32_t mine[8];
  uint32_t pmin = 0xFFFFFFFFu;
#pragma unroll
  for (int q = 0; q < 4; ++q) {
    u64 v = sp[lane + q * 64];
    mine[2 * q] = (uint32_t)(v >> 32);
    mine[2 * q + 1] = (uint32_t)v;
    pmin = min(pmin, mine[2 * q]);
  }
#pragma unroll
  for (int ms = 1; ms < 64; ms <<= 1) pmin = min(pmin, __shfl_xor(pmin, ms, 64));

  float xxf = xxArr[row];
  float smin_lb = key2f((pmin >> 14) << 14);
  float thr = smin_lb + ulpf(fabsf(xxf) + 0.03f) + 1e-4f;
  uint32_t kthr = f2key(thr) >> 14;

  int cnt = 0;
#pragma unroll
  for (int q = 0; q < 8; ++q) cnt += ((mine[q] >> 14) <= kthr) ? 1 : 0;
#pragma unroll
  for (int ms = 1; ms < 64; ms <<= 1) cnt += __shfl_xor(cnt, ms, 64);

  __shared__ int cand[4][32];
  __shared__ int ccount[4];
  bool need = (cnt > 1);
  if (lane == 0) ccount[w] = 0;
  __syncthreads();
  if (need) {
#pragma unroll
    for (int q = 0; q < 8; ++q) {
      if ((mine[q] >> 14) <= kthr) {
        int slot = atomicAdd(&ccount[w], 1);
        if (slot < 32) cand[w][slot] = (int)(mine[q] & 0x3FFFu);
      }
    }
  }
  __syncthreads();

  int winner;
  if (!need) {
    winner = (int)(pmin & 0x3FFFu);
  } else {
    int nc = min(ccount[w], 32);
    float bestd = FLT_MAX;
    int bestn = 0x7fffffff;
    const float* xr = x + (long)row * K_DIM;
    for (int c = 0; c < nc; ++c) {
      int n = cand[w][c];
      const float* er = emb + (long)n * K_DIM;
      double ds = 0.0;
      for (int k = lane; k < K_DIM; k += 64)
        ds += (double)xr[k] * (double)er[k];
#pragma unroll
      for (int ms = 1; ms < 64; ms <<= 1) ds += __shfl_xor(ds, ms, 64);
      float dotf = (float)ds;
      float t2 = 2.0f * dotf;
      float dq = xxf - t2;
      if (dq < bestd || (dq == bestd && n < bestn)) { bestd = dq; bestn = n; }
    }
    winner = bestn;
  }
  if (lane == 0) { outIdxF[row] = (float)winner; idxOut[row] = winner; }
}

// ---------------- gather z_q = embedding[idx] ----------------

__global__ void gather_kernel(const float* __restrict__ emb,
                              const int* __restrict__ idx,
                              float* __restrict__ zq) {
  int row = blockIdx.x, t = threadIdx.x;
  long n = idx[row];
  const float4* s = reinterpret_cast<const float4*>(emb + n * K_DIM);
  float4* d = reinterpret_cast<float4*>(zq + (long)row * K_DIM);
  d[t] = s[t];
  d[t + 256] = s[t + 256];
}

// ---------------- launch ----------------

extern "C" void kernel_launch(void* const* d_in, const int* in_sizes, int n_in,
                              void* d_out, int out_size, void* d_ws, size_t ws_size,
                              hipStream_t stream) {
  const float* x = (const float*)d_in[0];
  const float* emb = (const float*)d_in[1];
  float* out = (float*)d_out;

  char* ws = (char*)d_ws;
  ushort* xh = (ushort*)ws;                               // 64 MiB
  u64* stripes = (u64*)(ws + 67108864);                   // 32 MiB
  float* xxArr = (float*)(ws + 100663296);                // 64 KiB
  int* idxbuf = (int*)(ws + 100728832);                   // 64 KiB

  ushort* ehh = (ushort*)d_out;                           // 64 MiB (overlay, gather overwrites)

  tobf16_kernel<<<16384, 256, 0, stream>>>(x, xh);
  tobf16_kernel<<<16384, 256, 0, stream>>>(emb, ehh);
  xx_kernel<<<1024, 256, 0, stream>>>(x, xxArr);
  gemm_argmin_kernel<<<4096, 512, 0, stream>>>(xh, ehh, stripes);
  resolve_kernel<<<4096, 256, 0, stream>>>(stripes, x, emb, xxArr, out + 33554432, idxbuf);
  gather_kernel<<<16384, 256, 0, stream>>>(emb, idxbuf, out);
}

// Round 7
// 1270.705 us; speedup vs baseline: 1.1519x; 1.0566x over previous
//
#include <hip/hip_runtime.h>
#include <stdint.h>
#include <float.h>

#define K_DIM 2048
#define M_TOK 16384
#define N_EMB 16384
#define NKT 32  // K-tiles of 64

typedef __bf16 bf16x8 __attribute__((ext_vector_type(8)));
typedef float f32x4 __attribute__((ext_vector_type(4)));
typedef unsigned long long u64;

__device__ __forceinline__ ushort f2bf_rne(float f) {
  uint32_t u = __float_as_uint(f);
  u += 0x7FFFu + ((u >> 16) & 1u);
  return (ushort)(u >> 16);
}
__device__ __forceinline__ uint32_t f2key(float f) {
  uint32_t u = __float_as_uint(f);
  return (u & 0x80000000u) ? ~u : (u | 0x80000000u);
}
__device__ __forceinline__ float key2f(uint32_t k) {
  uint32_t b = (k & 0x80000000u) ? (k & 0x7FFFFFFFu) : ~k;
  return __uint_as_float(b);
}
__device__ __forceinline__ float ulpf(float v) {
  uint32_t e = __float_as_uint(v) & 0x7f800000u;
  return __uint_as_float(e) * 1.1920929e-7f;  // 2^-23
}

// ---------------- fp32 -> bf16 (RNE) ----------------

__global__ void tobf16_kernel(const float* __restrict__ in, ushort* __restrict__ out) {
  long i = ((long)blockIdx.x * 256 + threadIdx.x) * 8;
  float4 a = *reinterpret_cast<const float4*>(in + i);
  float4 b = *reinterpret_cast<const float4*>(in + i + 4);
  ushort4 ha, hb;
  ha.x = f2bf_rne(a.x); ha.y = f2bf_rne(a.y); ha.z = f2bf_rne(a.z); ha.w = f2bf_rne(a.w);
  hb.x = f2bf_rne(b.x); hb.y = f2bf_rne(b.y); hb.z = f2bf_rne(b.z); hb.w = f2bf_rne(b.w);
  *reinterpret_cast<ushort4*>(out + i) = ha;
  *reinterpret_cast<ushort4*>(out + i + 4) = hb;
}

// ------- xx = np.sum(x*x, axis=1) replicating numpy AVX512 pairwise_sum -------

__global__ void xx_kernel(const float* __restrict__ x, float* __restrict__ xxArr) {
#pragma clang fp contract(off)
  int row = blockIdx.x * 16 + (threadIdx.x >> 4);
  int blk = threadIdx.x & 15;
  const float* p = x + (long)row * K_DIM + blk * 128;
  float S[16];
#pragma unroll
  for (int L = 0; L < 16; ++L) {
    float p0 = p[L] * p[L];
    float p1 = p[L + 16] * p[L + 16];
    float p2 = p[L + 32] * p[L + 32];
    float p3 = p[L + 48] * p[L + 48];
    float p4 = p[L + 64] * p[L + 64];
    float p5 = p[L + 80] * p[L + 80];
    float p6 = p[L + 96] * p[L + 96];
    float p7 = p[L + 112] * p[L + 112];
    S[L] = ((p0 + p1) + (p2 + p3)) + ((p4 + p5) + (p6 + p7));
  }
  float T1[8], T3[4];
#pragma unroll
  for (int L = 0; L < 8; ++L) T1[L] = S[L] + S[L + 8];
#pragma unroll
  for (int L = 0; L < 4; ++L) T3[L] = T1[L] + T1[L + 4];
  float blksum = (T3[0] + T3[2]) + (T3[1] + T3[3]);
  __shared__ float lds[16][16];
  lds[threadIdx.x >> 4][blk] = blksum;
  __syncthreads();
  if (blk == 0) {
    const float* b = lds[threadIdx.x >> 4];
    float r1[8], r2[4];
#pragma unroll
    for (int i = 0; i < 8; ++i) r1[i] = b[2 * i] + b[2 * i + 1];
#pragma unroll
    for (int i = 0; i < 4; ++i) r2[i] = r1[2 * i] + r1[2 * i + 1];
    xxArr[row] = (r2[0] + r2[1]) + (r2[2] + r2[3]);
  }
}

// ---------------- bf16 GEMM + per-stripe top-2 coarse argmin ----------------
// 8-phase m201 port, RACE-FIXED staging map. 256x256 tile, BK=64, 8 waves
// (2m x 4n), wave 128x64. LDS 128 KiB: 2 dbuf x {A[256x64], B[256x64]}.
// Region readers (tile kt, buf BS): A-half-h read at P1,P3 (by wm=h waves);
// B-half-h read at P1,P2 (by wn waves). Legal stage points into live buf:
// B @ P3/P4, A @ P4 only; into other buf: any phase.
// Map: tile j: A1(j)@P1(j-1)->other buf; B0(j)@P3(j-2); B1(j),A0(j)@P4(j-2).
// vmcnt(6) at P4(kt) = {B0,B1,A0}(kt+2) in flight; all of kt+1 landed.
// XOR-swizzle chunk^(row&7) via pre-swizzled global source (rule #21).

#define GLOAD_LDS16(g, s)                                              \
  __builtin_amdgcn_global_load_lds(                                    \
      (const __attribute__((address_space(1))) void*)(g),              \
      (__attribute__((address_space(3))) void*)(s), 16, 0, 0)

__global__ __launch_bounds__(512, 2) void gemm_argmin_kernel(
    const ushort* __restrict__ xh, const ushort* __restrict__ eh,
    u64* __restrict__ stripes) {
  __shared__ __attribute__((aligned(16))) ushort lds[65536];  // 128 KiB

  int b = blockIdx.x;
  int wg = (b & 7) * 512 + (b >> 3);  // XCD-aware swizzle (4096 % 8 == 0)
  int bx = wg & 63, by = wg >> 6;
  int m0 = by * 256, n0 = bx * 256;

  int t = threadIdx.x;
  int lane = t & 63, wid = t >> 6;
  int wm = wid >> 2, wn = wid & 3;
  int arow = lane & 15;
  int kg8 = (lane >> 4) * 8;

  // staging: thread t covers row (t>>3) within each 64-row gload group,
  // chunk (t&7); global chunk pre-swizzled by ^(row&7) (both-sides rule).
  int srow = t >> 3;
  int swz8 = (((t & 7) ^ (srow & 7)) << 3);
  const ushort* gA = xh + (unsigned)(m0 + srow) * 2048u + swz8;
  const ushort* gB = eh + (unsigned)(n0 + srow) * 2048u + swz8;
  ushort* ldst = (ushort*)lds + t * 8;

  // one half-tile (128 rows x 64 cols) = 2 gloads. LOFF: A=0, B=16384.
#define STAGE_H(GSRC, H, KT, BS, LOFF)                                 \
  {                                                                    \
    const ushort* _g = (GSRC) + (H) * 262144 + (KT) * 64;              \
    ushort* _d = ldst + (BS) * 32768 + (LOFF) + (H) * 8192;            \
    GLOAD_LDS16(_g, _d);                                               \
    GLOAD_LDS16(_g + 131072, _d + 4096);                               \
  }

  f32x4 acc[8][4] = {};
  bf16x8 a[4][2], b0r[2][2], b1r[2][2];

  int xr = (arow & 7) << 3;
  int ck0 = kg8 ^ xr;          // swizzled col offset, k-step 0
  int ck1 = (32 + kg8) ^ xr;   // k-step 1
  const ushort* ldsA = (const ushort*)lds + (wm * 128 + arow) * 64;
  const ushort* ldsB = (const ushort*)lds + 16384 + (wn * 64 + arow) * 64;

#define RD_A(QA, BS)                                                   \
  _Pragma("unroll") for (int i4 = 0; i4 < 4; ++i4) {                   \
    a[i4][0] = *(const bf16x8*)(ldsA + (BS) * 32768 + ((QA) * 4 + i4) * 1024 + ck0); \
    a[i4][1] = *(const bf16x8*)(ldsA + (BS) * 32768 + ((QA) * 4 + i4) * 1024 + ck1); \
  }
#define RD_B(DST, QB, BS)                                              \
  _Pragma("unroll") for (int j2 = 0; j2 < 2; ++j2) {                   \
    DST[j2][0] = *(const bf16x8*)(ldsB + (BS) * 32768 + ((QB) * 2 + j2) * 1024 + ck0); \
    DST[j2][1] = *(const bf16x8*)(ldsB + (BS) * 32768 + ((QB) * 2 + j2) * 1024 + ck1); \
  }
#define MFMA_Q(QA, QB, BSRC)                                           \
  __builtin_amdgcn_s_setprio(1);                                       \
  _Pragma("unroll") for (int i4 = 0; i4 < 4; ++i4)                     \
  _Pragma("unroll") for (int j2 = 0; j2 < 2; ++j2) {                   \
    acc[(QA) * 4 + i4][(QB) * 2 + j2] = __builtin_amdgcn_mfma_f32_16x16x32_bf16( \
        a[i4][0], BSRC[j2][0], acc[(QA) * 4 + i4][(QB) * 2 + j2], 0, 0, 0);      \
    acc[(QA) * 4 + i4][(QB) * 2 + j2] = __builtin_amdgcn_mfma_f32_16x16x32_bf16( \
        a[i4][1], BSRC[j2][1], acc[(QA) * 4 + i4][(QB) * 2 + j2], 0, 0, 0);      \
  }                                                                    \
  __builtin_amdgcn_s_setprio(0);
#define BAR() __builtin_amdgcn_s_barrier()
#define VMC(N) asm volatile("s_waitcnt vmcnt(" #N ")" ::: "memory")

  // 4 phases of tile KT in buf BS; race-fixed staging map (see header).
#define TILE_STEADY(KT, BS)                                            \
  RD_A(0, BS); RD_B(b0r, 0, BS);                                       \
  STAGE_H(gA, 1, (KT) + 1, (BS) ^ 1, 0);                               \
  BAR(); MFMA_Q(0, 0, b0r); BAR();                                     \
  RD_B(b1r, 1, BS);                                                    \
  BAR(); MFMA_Q(0, 1, b1r); BAR();                                     \
  RD_A(1, BS);                                                         \
  STAGE_H(gB, 0, (KT) + 2, BS, 16384);                                 \
  BAR(); MFMA_Q(1, 1, b1r); BAR();                                     \
  STAGE_H(gB, 1, (KT) + 2, BS, 16384);                                 \
  STAGE_H(gA, 0, (KT) + 2, BS, 0);                                     \
  VMC(6); BAR(); MFMA_Q(1, 0, b0r); BAR();

  // prologue: tile0 full (8 gloads) + tile1's {B0,B1,A0} (6 gloads);
  // A1(1) is staged at P1(0) per the map.
  STAGE_H(gA, 0, 0, 0, 0); STAGE_H(gA, 1, 0, 0, 0);
  STAGE_H(gB, 0, 0, 0, 16384); STAGE_H(gB, 1, 0, 0, 16384);
  STAGE_H(gB, 0, 1, 1, 16384); STAGE_H(gB, 1, 1, 1, 16384);
  STAGE_H(gA, 0, 1, 1, 0);
  VMC(6);  // tile0's 8 landed; tile1's 6 in flight
  BAR();

#pragma unroll 1
  for (int kt = 0; kt < NKT - 2; kt += 2) {
    TILE_STEADY(kt, 0);
    TILE_STEADY(kt + 1, 1);
  }

  // tile 30 (buf0): stage only A1(31) at P1; drain at P4
  RD_A(0, 0); RD_B(b0r, 0, 0);
  STAGE_H(gA, 1, 31, 1, 0);
  BAR(); MFMA_Q(0, 0, b0r); BAR();
  RD_B(b1r, 1, 0);
  BAR(); MFMA_Q(0, 1, b1r); BAR();
  RD_A(1, 0);
  BAR(); MFMA_Q(1, 1, b1r); BAR();
  VMC(0); BAR(); MFMA_Q(1, 0, b0r); BAR();

  // tile 31 (buf1): no staging, no barriers (data-dep ordering)
  RD_A(0, 1); RD_B(b0r, 0, 1);
  MFMA_Q(0, 0, b0r);
  RD_B(b1r, 1, 1);
  MFMA_Q(0, 1, b1r);
  RD_A(1, 1);
  MFMA_Q(1, 1, b1r);
  MFMA_Q(1, 0, b0r);

  // epilogue: per-row top-2 over this wave's 64 columns; score = -2*dot
  int stripe = (bx << 2) + wn;  // 0..255
#pragma unroll
  for (int i = 0; i < 8; ++i) {
#pragma unroll
    for (int r = 0; r < 4; ++r) {
      uint32_t p1 = 0xFFFFFFFFu, p2 = 0xFFFFFFFFu;
#pragma unroll
      for (int j = 0; j < 4; ++j) {
        float sv = -2.0f * acc[i][j][r];
        uint32_t n = (uint32_t)(n0 + wn * 64 + j * 16 + arow);
        uint32_t pk = ((f2key(sv) >> 14) << 14) | n;
        if (pk < p1) { p2 = p1; p1 = pk; }
        else if (pk < p2) { p2 = pk; }
      }
#pragma unroll
      for (int ms = 1; ms < 16; ms <<= 1) {
        uint32_t q1 = __shfl_xor(p1, ms, 64);
        uint32_t q2 = __shfl_xor(p2, ms, 64);
        uint32_t m1 = min(p1, q1);
        uint32_t m2 = min(max(p1, q1), min(p2, q2));
        p1 = m1; p2 = m2;
      }
      if ((lane & 15) == 0) {
        long gm = m0 + wm * 128 + i * 16 + (lane >> 4) * 4 + r;
        stripes[gm * 256 + stripe] = ((u64)p1 << 32) | p2;
      }
    }
  }
#undef STAGE_H
#undef RD_A
#undef RD_B
#undef MFMA_Q
#undef TILE_STEADY
#undef BAR
#undef VMC
}

// ---- resolve: emulate np fp32 d = fl(xx - 2*fl(dot)), argmin, tie->lowest n ----

__global__ void resolve_kernel(const u64* __restrict__ stripes,
                               const float* __restrict__ x,
                               const float* __restrict__ emb,
                               const float* __restrict__ xxArr,
                               float* __restrict__ outIdxF,
                               int* __restrict__ idxOut) {
#pragma clang fp contract(off)
  int w = threadIdx.x >> 6;
  int row = blockIdx.x * 4 + w;
  int lane = threadIdx.x & 63;
  const u64* sp = stripes + (long)row * 256;

  uint32_t mine[8];
  uint32_t pmin = 0xFFFFFFFFu;
#pragma unroll
  for (int q = 0; q < 4; ++q) {
    u64 v = sp[lane + q * 64];
    mine[2 * q] = (uint32_t)(v >> 32);
    mine[2 * q + 1] = (uint32_t)v;
    pmin = min(pmin, mine[2 * q]);
  }
#pragma unroll
  for (int ms = 1; ms < 64; ms <<= 1) pmin = min(pmin, __shfl_xor(pmin, ms, 64));

  float xxf = xxArr[row];
  float smin_lb = key2f((pmin >> 14) << 14);
  float thr = smin_lb + ulpf(fabsf(xxf) + 0.03f) + 1e-4f;
  uint32_t kthr = f2key(thr) >> 14;

  int cnt = 0;
#pragma unroll
  for (int q = 0; q < 8; ++q) cnt += ((mine[q] >> 14) <= kthr) ? 1 : 0;
#pragma unroll
  for (int ms = 1; ms < 64; ms <<= 1) cnt += __shfl_xor(cnt, ms, 64);

  __shared__ int cand[4][32];
  __shared__ int ccount[4];
  bool need = (cnt > 1);
  if (lane == 0) ccount[w] = 0;
  __syncthreads();
  if (need) {
#pragma unroll
    for (int q = 0; q < 8; ++q) {
      if ((mine[q] >> 14) <= kthr) {
        int slot = atomicAdd(&ccount[w], 1);
        if (slot < 32) cand[w][slot] = (int)(mine[q] & 0x3FFFu);
      }
    }
  }
  __syncthreads();

  int winner;
  if (!need) {
    winner = (int)(pmin & 0x3FFFu);
  } else {
    int nc = min(ccount[w], 32);
    float bestd = FLT_MAX;
    int bestn = 0x7fffffff;
    const float* xr = x + (long)row * K_DIM;
    for (int c = 0; c < nc; ++c) {
      int n = cand[w][c];
      const float* er = emb + (long)n * K_DIM;
      double ds = 0.0;
      for (int k = lane; k < K_DIM; k += 64)
        ds += (double)xr[k] * (double)er[k];
#pragma unroll
      for (int ms = 1; ms < 64; ms <<= 1) ds += __shfl_xor(ds, ms, 64);
      float dotf = (float)ds;
      float t2 = 2.0f * dotf;
      float dq = xxf - t2;
      if (dq < bestd || (dq == bestd && n < bestn)) { bestd = dq; bestn = n; }
    }
    winner = bestn;
  }
  if (lane == 0) { outIdxF[row] = (float)winner; idxOut[row] = winner; }
}

// ---------------- gather z_q = embedding[idx] ----------------

__global__ void gather_kernel(const float* __restrict__ emb,
                              const int* __restrict__ idx,
                              float* __restrict__ zq) {
  int row = blockIdx.x, t = threadIdx.x;
  long n = idx[row];
  const float4* s = reinterpret_cast<const float4*>(emb + n * K_DIM);
  float4* d = reinterpret_cast<float4*>(zq + (long)row * K_DIM);
  d[t] = s[t];
  d[t + 256] = s[t + 256];
}

// ---------------- launch ----------------

extern "C" void kernel_launch(void* const* d_in, const int* in_sizes, int n_in,
                              void* d_out, int out_size, void* d_ws, size_t ws_size,
                              hipStream_t stream) {
  const float* x = (const float*)d_in[0];
  const float* emb = (const float*)d_in[1];
  float* out = (float*)d_out;

  char* ws = (char*)d_ws;
  ushort* xh = (ushort*)ws;                               // 64 MiB
  u64* stripes = (u64*)(ws + 67108864);                   // 32 MiB
  float* xxArr = (float*)(ws + 100663296);                // 64 KiB
  int* idxbuf = (int*)(ws + 100728832);                   // 64 KiB

  ushort* ehh = (ushort*)d_out;                           // 64 MiB (overlay, gather overwrites)

  tobf16_kernel<<<16384, 256, 0, stream>>>(x, xh);
  tobf16_kernel<<<16384, 256, 0, stream>>>(emb, ehh);
  xx_kernel<<<1024, 256, 0, stream>>>(x, xxArr);
  gemm_argmin_kernel<<<4096, 512, 0, stream>>>(xh, ehh, stripes);
  resolve_kernel<<<4096, 256, 0, stream>>>(stripes, x, emb, xxArr, out + 33554432, idxbuf);
  gather_kernel<<<16384, 256, 0, stream>>>(emb, idxbuf, out);
}